// Round 5
// baseline (434.973 us; speedup 1.0000x reference)
//
#include <hip/hip_runtime.h>
#include <math.h>

// ---------------- problem constants ----------------
#define N        2048
#define NT       256      // threads per block
#define NSC      81       // number of scales (J+1)
#define BATCH    64
#define WS_WIN   94       // sliding window = 32*3-2
#define NOUT     1955     // N - WS_WIN + 1
#define DT_S     0.1f
#define W0_C     6.0f
#define PI_F     3.14159265358979f
#define TWOPI_F  6.28318530717959f
#define PIM14    0.7511255444649425f   // pi^(-1/4)
#define C_SQ2H   0.70710678118654752f  // sqrt(2)/2

// pad-swizzle: +1 element every 16 keeps every stage's b64 pattern at the
// 4-lane/bank-pair bandwidth floor
#define SWZ(e)   ((e) + ((e) >> 4))
#define LDSN     2176     // 2048 + 128 pad elements

__device__ __forceinline__ float2 cadd2(float2 a, float2 b) { return make_float2(a.x + b.x, a.y + b.y); }
__device__ __forceinline__ float2 csub2(float2 a, float2 b) { return make_float2(a.x - b.x, a.y - b.y); }
__device__ __forceinline__ float2 cmul2(float2 a, float2 b) { return make_float2(a.x * b.x - a.y * b.y, a.x * b.y + a.y * b.x); }

// 8-point DFT, natural-order outputs (sign SGN)
template<int SGN>
__device__ __forceinline__ void dft8(const float2 (&x)[8], float2 (&y)[8]) {
    const float s = (float)SGN;
    float2 t0 = cadd2(x[0], x[4]), t1 = cadd2(x[1], x[5]);
    float2 t2 = cadd2(x[2], x[6]), t3 = cadd2(x[3], x[7]);
    float2 u0 = csub2(x[0], x[4]);
    float2 d1 = csub2(x[1], x[5]);
    float2 d2 = csub2(x[2], x[6]);
    float2 d3 = csub2(x[3], x[7]);
    float2 u1 = make_float2(C_SQ2H * (d1.x - s * d1.y), C_SQ2H * (d1.y + s * d1.x));
    float2 u2 = make_float2(-s * d2.y, s * d2.x);
    float2 u3 = make_float2(-C_SQ2H * (d3.x + s * d3.y), C_SQ2H * (s * d3.x - d3.y));
    float2 a0 = cadd2(t0, t2), a1 = cadd2(t1, t3), b0 = csub2(t0, t2), e1 = csub2(t1, t3);
    float2 b1 = make_float2(-s * e1.y, s * e1.x);
    y[0] = cadd2(a0, a1); y[4] = csub2(a0, a1); y[2] = cadd2(b0, b1); y[6] = csub2(b0, b1);
    float2 c0 = cadd2(u0, u2), c1 = cadd2(u1, u3), g0 = csub2(u0, u2), h1 = csub2(u1, u3);
    float2 g1 = make_float2(-s * h1.y, s * h1.x);
    y[1] = cadd2(c0, c1); y[5] = csub2(c0, c1); y[3] = cadd2(g0, g1); y[7] = csub2(g0, g1);
}

// twiddle by w^u (w = exp(SGN*2pi*i*jm/N)) and scatter-store
template<int SGN>
__device__ __forceinline__ void twiddle_store(const float2 (&y)[8], float2* __restrict__ dst,
                                              int jm, int base, int m) {
    float ang = (float)SGN * (TWOPI_F / (float)N) * (float)jm;
    float sn, cs; __sincosf(ang, &sn, &cs);
    float2 w1 = make_float2(cs, sn);
    float2 w2 = cmul2(w1, w1);
    float2 w3 = cmul2(w2, w1);
    float2 w4 = cmul2(w2, w2);
    float2 w5 = cmul2(w3, w2);
    float2 w6 = cmul2(w3, w3);
    float2 w7 = cmul2(w4, w3);
    dst[SWZ(base)]         = y[0];
    dst[SWZ(base + m)]     = cmul2(y[1], w1);
    dst[SWZ(base + 2 * m)] = cmul2(y[2], w2);
    dst[SWZ(base + 3 * m)] = cmul2(y[3], w3);
    dst[SWZ(base + 4 * m)] = cmul2(y[4], w4);
    dst[SWZ(base + 5 * m)] = cmul2(y[5], w5);
    dst[SWZ(base + 6 * m)] = cmul2(y[6], w6);
    dst[SWZ(base + 7 * m)] = cmul2(y[7], w7);
}

// stage 1 (m=1): input from registers x[p] = element tid + p*256
template<int SGN>
__device__ __forceinline__ void stage1_reg(const float2 (&x)[8], float2* __restrict__ dst, int tid) {
    float2 y[8];
    dft8<SGN>(x, y);
    twiddle_store<SGN>(y, dst, tid, 8 * tid, 1);
}

// middle radix-8 stage, LDS -> LDS
template<int SGN>
__device__ __forceinline__ void stage8_lds(const float2* __restrict__ src,
                                           float2* __restrict__ dst, int q, int shift) {
    float2 xin[8];
    #pragma unroll
    for (int p = 0; p < 8; ++p) xin[p] = src[SWZ(q + p * 256)];
    float2 y[8];
    dft8<SGN>(xin, y);
    const int m  = 1 << shift;
    const int jm = q & ~(m - 1);
    twiddle_store<SGN>(y, dst, jm, q + 7 * jm, m);
}

// final radix-4 stage (m=512, j=0, no twiddles): outputs land back in regs,
// x[2u+qq] = element tid + (2u+qq)*256  (natural order, thread-owned)
template<int SGN>
__device__ __forceinline__ void stage4_regs(const float2* __restrict__ src, float2 (&x)[8], int tid) {
    const float s = (float)SGN;
    #pragma unroll
    for (int qq = 0; qq < 2; ++qq) {
        int q = tid + qq * 256;
        float2 x0 = src[SWZ(q)];
        float2 x1 = src[SWZ(q + 512)];
        float2 x2 = src[SWZ(q + 1024)];
        float2 x3 = src[SWZ(q + 1536)];
        float2 a0 = cadd2(x0, x2), a1 = cadd2(x1, x3);
        float2 b0 = csub2(x0, x2), e1 = csub2(x1, x3);
        float2 b1 = make_float2(-s * e1.y, s * e1.x);
        x[0 + qq] = cadd2(a0, a1);
        x[2 + qq] = cadd2(b0, b1);
        x[4 + qq] = csub2(a0, a1);
        x[6 + qq] = csub2(b0, b1);
    }
}

// full 2048-pt FFT, register in / register out (x[i] = element tid + i*256).
// SGN=-1: forward (numpy fft). SGN=+1: inverse exponent (1/N not applied).
template<int SGN>
__device__ __forceinline__ void fft2048_reg(float2 (&x)[8], float2* A, float2* B, int tid) {
    __syncthreads();                     // protect B from previous FFT's reads
    stage1_reg<SGN>(x, B, tid);          // regs -> B   (m=1)
    __syncthreads();
    stage8_lds<SGN>(B, A, tid, 3);       // B -> A      (m=8)
    __syncthreads();
    stage8_lds<SGN>(A, B, tid, 6);       // A -> B      (m=64)
    __syncthreads();
    stage4_regs<SGN>(B, x, tid);         // B -> regs   (m=512)
}

// ---------------- K1: normalize + forward FFT of each signal ----------------
__global__ __launch_bounds__(NT) void k_fft_in(const float* __restrict__ x,
                                               float2* __restrict__ spec) {
    __shared__ float2 A[LDSN];
    __shared__ float2 B[LDSN];
    __shared__ float  rs[NT], rq[NT];
    const int    tid = threadIdx.x;
    const float* y   = x + (size_t)blockIdx.x * N;

    float v[8];
    float lsum = 0.f, lsq = 0.f;
    #pragma unroll
    for (int i = 0; i < 8; ++i) {
        float t = y[tid + i * NT];
        v[i] = t; lsum += t; lsq += t * t;
    }
    rs[tid] = lsum; rq[tid] = lsq;
    __syncthreads();
    for (int o = NT / 2; o > 0; o >>= 1) {
        if (tid < o) { rs[tid] += rs[tid + o]; rq[tid] += rq[tid + o]; }
        __syncthreads();
    }
    const float mean = rs[0] * (1.f / N);
    const float var  = rq[0] * (1.f / N) - mean * mean;
    const float inv  = rsqrtf(var);

    float2 z[8];
    #pragma unroll
    for (int i = 0; i < 8; ++i) z[i] = make_float2((v[i] - mean) * inv, 0.f);

    fft2048_reg<-1>(z, A, B, tid);

    float2* o2 = spec + (size_t)blockIdx.x * N;
    #pragma unroll
    for (int i = 0; i < 8; ++i) o2[tid + i * NT] = z[i];
}

// ---------------- K2: per (batch, scale) CWT + smoothing ----------------
// NO __launch_bounds__: default 1024-thread bound caps VGPR at 128 (4 waves/
// SIMD guaranteed) and the restructured live set (~90 regs: one float2[8]
// array live across each FFT, P-chain finished & stored before C-chain
// starts, Morlet filter recomputed instead of kept live) fits without spill.
// R3/(256,4)->64 VGPR and R4/(256,3)->84 VGPR both spilled ~140-380 MB.
__global__ void k_wct(const float2* __restrict__ spec,
                      float2* __restrict__ Tp, float2* __restrict__ Tc, int b0) {
    __shared__ float2 A[LDSN];
    __shared__ float2 B[LDSN];
    const int tid  = threadIdx.x;
    const int sidx = blockIdx.x % NSC;
    const int bl   = blockIdx.x / NSC;
    const int b    = b0 + bl;

    const float s0    = 2.f * DT_S * (W0_C + sqrtf(2.f + W0_C * W0_C)) / (4.f * PI_F);
    const float s     = s0 * exp2f(0.125f * (float)sidx);
    const float inv_s = 1.f / s;

    const float2* yh1 = spec + (size_t)(b * 2 + 0) * N;
    const float2* yh2 = spec + (size_t)(b * 2 + 1) * N;

    // Morlet filter (w>0 one-sided), unit-energy norm, ifft 1/N folded in
    const float nrm   = PIM14 * sqrtf(TWOPI_F * s / DT_S) * (1.f / N);
    const float wstep = TWOPI_F / ((float)N * DT_S);

    float2 w1[8];
    #pragma unroll
    for (int i = 0; i < 8; ++i) {
        int   k = tid + i * NT;
        float f = 0.f;
        if (k >= 1 && k < N / 2) {
            float arg = s * (wstep * (float)k) - W0_C;
            f = nrm * expf(-0.5f * arg * arg);
        }
        float2 a = yh1[k];
        w1[i] = make_float2(a.x * f, a.y * f);
    }
    fft2048_reg<+1>(w1, A, B, tid);        // W1 in regs

    float2 w2[8];
    #pragma unroll
    for (int i = 0; i < 8; ++i) {
        int   k = tid + i * NT;
        float f = 0.f;                      // recompute filter (frees fm regs)
        if (k >= 1 && k < N / 2) {
            float arg = s * (wstep * (float)k) - W0_C;
            f = nrm * expf(-0.5f * arg * arg);
        }
        float2 c = yh2[k];
        w2[i] = make_float2(c.x * f, c.y * f);
    }
    fft2048_reg<+1>(w2, A, B, tid);        // W2 in regs (w1 live)

    // pointwise products in registers; w1/w2 die here
    float2 P[8], C[8];
    #pragma unroll
    for (int i = 0; i < 8; ++i) {
        float2 a = w1[i], c = w2[i];
        P[i] = make_float2((a.x * a.x + a.y * a.y) * inv_s,
                           (c.x * c.x + c.y * c.y) * inv_s);
        C[i] = make_float2((a.x * c.x + a.y * c.y) * inv_s,
                           (a.y * c.x - a.x * c.y) * inv_s);
    }

    // Gaussian time-smoothing in Fourier domain (1/N folded into F)
    const float sdt = s / DT_S;
    const float fc  = -0.5f * sdt * sdt * (TWOPI_F / (float)N) * (TWOPI_F / (float)N);

    // --- P chain first; store, then P dies before C chain starts ---
    fft2048_reg<-1>(P, A, B, tid);
    #pragma unroll
    for (int i = 0; i < 8; ++i) {
        int   k  = tid + i * NT;
        int   mk = min(k, N - k);
        float F  = expf(fc * (float)(mk * mk)) * (1.f / N);
        P[i].x *= F; P[i].y *= F;
    }
    fft2048_reg<+1>(P, A, B, tid);         // Psm in regs

    float2* Tpo = Tp + ((size_t)bl * NSC + sidx) * N;
    #pragma unroll
    for (int i = 0; i < 8; ++i) Tpo[tid + i * NT] = P[i];

    // --- C chain ---
    fft2048_reg<-1>(C, A, B, tid);
    #pragma unroll
    for (int i = 0; i < 8; ++i) {
        int   k  = tid + i * NT;
        int   mk = min(k, N - k);
        float F  = expf(fc * (float)(mk * mk)) * (1.f / N);
        C[i].x *= F; C[i].y *= F;
    }
    fft2048_reg<+1>(C, A, B, tid);         // Csm in regs

    float2* Tco = Tc + ((size_t)bl * NSC + sidx) * N;
    #pragma unroll
    for (int i = 0; i < 8; ++i) Tco[tid + i * NT] = C[i];
}

// ---------------- K3: scale-axis boxcar conv + coherence + scale sum --------
__global__ __launch_bounds__(NT) void k_coh(const float2* __restrict__ Tp,
                                            const float2* __restrict__ Tc,
                                            float* __restrict__ coh, int b0) {
    const int bl = blockIdx.x >> 3;
    const int t  = ((blockIdx.x & 7) << 8) + threadIdx.x;
    const int b  = b0 + bl;
    const float2* colp = Tp + (size_t)bl * NSC * N + t;
    const float2* colc = Tc + (size_t)bl * NSC * N + t;

    float2 qp[10], qc[10];
    #pragma unroll
    for (int i = 0; i < 10; ++i) { qp[i] = make_float2(0.f, 0.f); qc[i] = make_float2(0.f, 0.f); }
    #pragma unroll
    for (int i = 0; i < 5; ++i) {
        qp[5 + i] = colp[(size_t)i * N];
        qc[5 + i] = colc[(size_t)i * N];
    }

    float acc = 0.f;
    const float w9 = 1.f / 9.f;
    for (int i = 0; i < NSC; ++i) {
        float sx = 0.f, sy = 0.f, sz = 0.f, sw = 0.f;
        #pragma unroll
        for (int k = 0; k < 10; ++k) { sx += qp[k].x; sy += qp[k].y; sz += qc[k].x; sw += qc[k].y; }
        float s1 = (sx - 0.5f * (qp[0].x + qp[9].x)) * w9;
        float s2 = (sy - 0.5f * (qp[0].y + qp[9].y)) * w9;
        float sr = (sz - 0.5f * (qc[0].x + qc[9].x)) * w9;
        float si = (sw - 0.5f * (qc[0].y + qc[9].y)) * w9;
        acc += (sr * sr + si * si) / (s1 * s2);
        #pragma unroll
        for (int k = 0; k < 9; ++k) { qp[k] = qp[k + 1]; qc[k] = qc[k + 1]; }
        int c = i + 5;
        if (c < NSC) {
            qp[9] = colp[(size_t)c * N];
            qc[9] = colc[(size_t)c * N];
        } else {
            qp[9] = make_float2(0.f, 0.f);
            qc[9] = make_float2(0.f, 0.f);
        }
    }
    coh[(size_t)b * N + t] = acc;
}

// ---------------- K4: sliding-window sum over time ----------------
__global__ __launch_bounds__(NT) void k_win(const float* __restrict__ coh,
                                            float* __restrict__ out) {
    __shared__ float row[N];
    const int b   = blockIdx.x;
    const int tid = threadIdx.x;
    for (int i = tid; i < N; i += NT) row[i] = coh[(size_t)b * N + i];
    __syncthreads();
    for (int t0 = tid; t0 < NOUT; t0 += NT) {
        float ssum = 0.f;
        for (int k = 0; k < WS_WIN; ++k) ssum += row[t0 + k];
        out[(size_t)b * NOUT + t0] = ssum;
    }
}

// ---------------- host launcher ----------------
extern "C" void kernel_launch(void* const* d_in, const int* in_sizes, int n_in,
                              void* d_out, int out_size, void* d_ws, size_t ws_size,
                              hipStream_t stream) {
    const float* x   = (const float*)d_in[0];
    float*       out = (float*)d_out;
    char*        ws  = (char*)d_ws;

    const size_t spec_bytes = (size_t)BATCH * 2 * N * sizeof(float2); // 2 MB
    const size_t coh_bytes  = (size_t)BATCH * N * sizeof(float);      // 512 KB
    const size_t perBatchT  = (size_t)NSC * N * sizeof(float4);       // Tp+Tc per batch

    float2* spec = (float2*)ws;
    float*  coh  = (float*)(ws + spec_bytes);
    char*   Tbase = ws + spec_bytes + coh_bytes;

    size_t avail = (ws_size > spec_bytes + coh_bytes) ? (ws_size - spec_bytes - coh_bytes) : 0;
    int chunk = (int)(avail / perBatchT);
    if (chunk < 1) chunk = 1;
    if (chunk > BATCH) chunk = BATCH;

    // planar layout: Tp plane then Tc plane, each chunk*NSC*N float2
    float2* Tp = (float2*)Tbase;
    float2* Tc = Tp + (size_t)chunk * NSC * N;

    k_fft_in<<<BATCH * 2, NT, 0, stream>>>(x, spec);
    for (int b0 = 0; b0 < BATCH; b0 += chunk) {
        int cb = BATCH - b0 < chunk ? BATCH - b0 : chunk;
        k_wct<<<cb * NSC, NT, 0, stream>>>(spec, Tp, Tc, b0);
        k_coh<<<cb * 8, NT, 0, stream>>>(Tp, Tc, coh, b0);
    }
    k_win<<<BATCH, NT, 0, stream>>>(coh, out);
}

// Round 6
// 431.809 us; speedup vs baseline: 1.0073x; 1.0073x over previous
//
#include <hip/hip_runtime.h>
#include <math.h>

// ---------------- problem constants ----------------
#define N        2048
#define NT       256      // threads per block
#define NSC      81       // number of scales (J+1)
#define BATCH    64
#define WS_WIN   94       // sliding window = 32*3-2
#define NOUT     1955     // N - WS_WIN + 1
#define DT_S     0.1f
#define W0_C     6.0f
#define PI_F     3.14159265358979f
#define TWOPI_F  6.28318530717959f
#define PIM14    0.7511255444649425f   // pi^(-1/4)
#define C_SQ2H   0.70710678118654752f  // sqrt(2)/2

// pad-swizzle: +1 element every 16 keeps every stage's b64 pattern at the
// 4-lane/bank-pair bandwidth floor
#define SWZ(e)   ((e) + ((e) >> 4))
#define LDSN     2176     // 2048 + 128 pad elements

__device__ __forceinline__ float2 cadd2(float2 a, float2 b) { return make_float2(a.x + b.x, a.y + b.y); }
__device__ __forceinline__ float2 csub2(float2 a, float2 b) { return make_float2(a.x - b.x, a.y - b.y); }
__device__ __forceinline__ float2 cmul2(float2 a, float2 b) { return make_float2(a.x * b.x - a.y * b.y, a.x * b.y + a.y * b.x); }

// 8-point DFT, natural-order outputs (sign SGN)
template<int SGN>
__device__ __forceinline__ void dft8(const float2 (&x)[8], float2 (&y)[8]) {
    const float s = (float)SGN;
    float2 t0 = cadd2(x[0], x[4]), t1 = cadd2(x[1], x[5]);
    float2 t2 = cadd2(x[2], x[6]), t3 = cadd2(x[3], x[7]);
    float2 u0 = csub2(x[0], x[4]);
    float2 d1 = csub2(x[1], x[5]);
    float2 d2 = csub2(x[2], x[6]);
    float2 d3 = csub2(x[3], x[7]);
    float2 u1 = make_float2(C_SQ2H * (d1.x - s * d1.y), C_SQ2H * (d1.y + s * d1.x));
    float2 u2 = make_float2(-s * d2.y, s * d2.x);
    float2 u3 = make_float2(-C_SQ2H * (d3.x + s * d3.y), C_SQ2H * (s * d3.x - d3.y));
    float2 a0 = cadd2(t0, t2), a1 = cadd2(t1, t3), b0 = csub2(t0, t2), e1 = csub2(t1, t3);
    float2 b1 = make_float2(-s * e1.y, s * e1.x);
    y[0] = cadd2(a0, a1); y[4] = csub2(a0, a1); y[2] = cadd2(b0, b1); y[6] = csub2(b0, b1);
    float2 c0 = cadd2(u0, u2), c1 = cadd2(u1, u3), g0 = csub2(u0, u2), h1 = csub2(u1, u3);
    float2 g1 = make_float2(-s * h1.y, s * h1.x);
    y[1] = cadd2(c0, c1); y[5] = csub2(c0, c1); y[3] = cadd2(g0, g1); y[7] = csub2(g0, g1);
}

// twiddle by w^u (w = exp(SGN*2pi*i*jm/N)) and scatter-store
template<int SGN>
__device__ __forceinline__ void twiddle_store(const float2 (&y)[8], float2* __restrict__ dst,
                                              int jm, int base, int m) {
    float ang = (float)SGN * (TWOPI_F / (float)N) * (float)jm;
    float sn, cs; __sincosf(ang, &sn, &cs);
    float2 w1 = make_float2(cs, sn);
    float2 w2 = cmul2(w1, w1);
    float2 w3 = cmul2(w2, w1);
    float2 w4 = cmul2(w2, w2);
    float2 w5 = cmul2(w3, w2);
    float2 w6 = cmul2(w3, w3);
    float2 w7 = cmul2(w4, w3);
    dst[SWZ(base)]         = y[0];
    dst[SWZ(base + m)]     = cmul2(y[1], w1);
    dst[SWZ(base + 2 * m)] = cmul2(y[2], w2);
    dst[SWZ(base + 3 * m)] = cmul2(y[3], w3);
    dst[SWZ(base + 4 * m)] = cmul2(y[4], w4);
    dst[SWZ(base + 5 * m)] = cmul2(y[5], w5);
    dst[SWZ(base + 6 * m)] = cmul2(y[6], w6);
    dst[SWZ(base + 7 * m)] = cmul2(y[7], w7);
}

// stage 1 (m=1): input from registers x[p] = element tid + p*256
template<int SGN>
__device__ __forceinline__ void stage1_reg(const float2 (&x)[8], float2* __restrict__ dst, int tid) {
    float2 y[8];
    dft8<SGN>(x, y);
    twiddle_store<SGN>(y, dst, tid, 8 * tid, 1);
}

// middle radix-8 stage, LDS -> LDS
template<int SGN>
__device__ __forceinline__ void stage8_lds(const float2* __restrict__ src,
                                           float2* __restrict__ dst, int q, int shift) {
    float2 xin[8];
    #pragma unroll
    for (int p = 0; p < 8; ++p) xin[p] = src[SWZ(q + p * 256)];
    float2 y[8];
    dft8<SGN>(xin, y);
    const int m  = 1 << shift;
    const int jm = q & ~(m - 1);
    twiddle_store<SGN>(y, dst, jm, q + 7 * jm, m);
}

// final radix-4 stage (m=512, j=0, no twiddles): outputs land back in regs,
// x[2u+qq] = element tid + (2u+qq)*256  (natural order, thread-owned)
template<int SGN>
__device__ __forceinline__ void stage4_regs(const float2* __restrict__ src, float2 (&x)[8], int tid) {
    const float s = (float)SGN;
    #pragma unroll
    for (int qq = 0; qq < 2; ++qq) {
        int q = tid + qq * 256;
        float2 x0 = src[SWZ(q)];
        float2 x1 = src[SWZ(q + 512)];
        float2 x2 = src[SWZ(q + 1024)];
        float2 x3 = src[SWZ(q + 1536)];
        float2 a0 = cadd2(x0, x2), a1 = cadd2(x1, x3);
        float2 b0 = csub2(x0, x2), e1 = csub2(x1, x3);
        float2 b1 = make_float2(-s * e1.y, s * e1.x);
        x[0 + qq] = cadd2(a0, a1);
        x[2 + qq] = cadd2(b0, b1);
        x[4 + qq] = csub2(a0, a1);
        x[6 + qq] = csub2(b0, b1);
    }
}

// full 2048-pt FFT, register in / register out (x[i] = element tid + i*256).
// SGN=-1: forward (numpy fft). SGN=+1: inverse exponent (1/N not applied).
template<int SGN>
__device__ __forceinline__ void fft2048_reg(float2 (&x)[8], float2* A, float2* B, int tid) {
    __syncthreads();                     // protect B from previous FFT's reads
    stage1_reg<SGN>(x, B, tid);          // regs -> B   (m=1)
    __syncthreads();
    stage8_lds<SGN>(B, A, tid, 3);       // B -> A      (m=8)
    __syncthreads();
    stage8_lds<SGN>(A, B, tid, 6);       // A -> B      (m=64)
    __syncthreads();
    stage4_regs<SGN>(B, x, tid);         // B -> regs   (m=512)
}

// ---------------- K1: normalize + forward FFT of each signal ----------------
__global__ __launch_bounds__(NT) void k_fft_in(const float* __restrict__ x,
                                               float2* __restrict__ spec) {
    __shared__ float2 A[LDSN];
    __shared__ float2 B[LDSN];
    __shared__ float  rs[NT], rq[NT];
    const int    tid = threadIdx.x;
    const float* y   = x + (size_t)blockIdx.x * N;

    float v[8];
    float lsum = 0.f, lsq = 0.f;
    #pragma unroll
    for (int i = 0; i < 8; ++i) {
        float t = y[tid + i * NT];
        v[i] = t; lsum += t; lsq += t * t;
    }
    rs[tid] = lsum; rq[tid] = lsq;
    __syncthreads();
    for (int o = NT / 2; o > 0; o >>= 1) {
        if (tid < o) { rs[tid] += rs[tid + o]; rq[tid] += rq[tid + o]; }
        __syncthreads();
    }
    const float mean = rs[0] * (1.f / N);
    const float var  = rq[0] * (1.f / N) - mean * mean;
    const float inv  = rsqrtf(var);

    float2 z[8];
    #pragma unroll
    for (int i = 0; i < 8; ++i) z[i] = make_float2((v[i] - mean) * inv, 0.f);

    fft2048_reg<-1>(z, A, B, tid);

    float2* o2 = spec + (size_t)blockIdx.x * N;
    #pragma unroll
    for (int i = 0; i < 8; ++i) o2[tid + i * NT] = z[i];
}

// ---------------- K2: per (batch, scale) CWT + smoothing ----------------
// amdgpu_waves_per_eu(4,4): pins BOTH min and max occupancy to 4 waves/EU ->
// VGPR budget 512/4 = 128 with no allocator incentive to shrink below it.
// Evidence: launch_bounds 2nd arg only sets the MIN; allocator still targeted
// 8 waves/EU (64 VGPR) and spilled 0.2-1.4 GB in R3/R4/R5. Peak live set of
// this structure is ~90-100 regs -> fits in 128 with zero spill.
// LDS 2x17KB also gives exactly 4 blocks/CU: occupancy-consistent.
__global__ __attribute__((amdgpu_waves_per_eu(4, 4))) __launch_bounds__(NT)
void k_wct(const float2* __restrict__ spec,
           float2* __restrict__ Tp, float2* __restrict__ Tc, int b0) {
    __shared__ float2 A[LDSN];
    __shared__ float2 B[LDSN];
    const int tid  = threadIdx.x;
    const int sidx = blockIdx.x % NSC;
    const int bl   = blockIdx.x / NSC;
    const int b    = b0 + bl;

    const float s0    = 2.f * DT_S * (W0_C + sqrtf(2.f + W0_C * W0_C)) / (4.f * PI_F);
    const float s     = s0 * exp2f(0.125f * (float)sidx);
    const float inv_s = 1.f / s;

    const float2* yh1 = spec + (size_t)(b * 2 + 0) * N;
    const float2* yh2 = spec + (size_t)(b * 2 + 1) * N;

    // Morlet filter (w>0 one-sided), unit-energy norm, ifft 1/N folded in
    const float nrm   = PIM14 * sqrtf(TWOPI_F * s / DT_S) * (1.f / N);
    const float wstep = TWOPI_F / ((float)N * DT_S);

    float2 w1[8];
    #pragma unroll
    for (int i = 0; i < 8; ++i) {
        int   k = tid + i * NT;
        float f = 0.f;
        if (k >= 1 && k < N / 2) {
            float arg = s * (wstep * (float)k) - W0_C;
            f = nrm * expf(-0.5f * arg * arg);
        }
        float2 a = yh1[k];
        w1[i] = make_float2(a.x * f, a.y * f);
    }
    fft2048_reg<+1>(w1, A, B, tid);        // W1 in regs

    float2 w2[8];
    #pragma unroll
    for (int i = 0; i < 8; ++i) {
        int   k = tid + i * NT;
        float f = 0.f;                      // recompute filter (frees fm regs)
        if (k >= 1 && k < N / 2) {
            float arg = s * (wstep * (float)k) - W0_C;
            f = nrm * expf(-0.5f * arg * arg);
        }
        float2 c = yh2[k];
        w2[i] = make_float2(c.x * f, c.y * f);
    }
    fft2048_reg<+1>(w2, A, B, tid);        // W2 in regs (w1 live)

    // pointwise products in registers; w1/w2 die here
    float2 P[8], C[8];
    #pragma unroll
    for (int i = 0; i < 8; ++i) {
        float2 a = w1[i], c = w2[i];
        P[i] = make_float2((a.x * a.x + a.y * a.y) * inv_s,
                           (c.x * c.x + c.y * c.y) * inv_s);
        C[i] = make_float2((a.x * c.x + a.y * c.y) * inv_s,
                           (a.y * c.x - a.x * c.y) * inv_s);
    }

    // Gaussian time-smoothing in Fourier domain (1/N folded into F)
    const float sdt = s / DT_S;
    const float fc  = -0.5f * sdt * sdt * (TWOPI_F / (float)N) * (TWOPI_F / (float)N);

    // --- P chain first; store, then P dies before C chain starts ---
    fft2048_reg<-1>(P, A, B, tid);
    #pragma unroll
    for (int i = 0; i < 8; ++i) {
        int   k  = tid + i * NT;
        int   mk = min(k, N - k);
        float F  = expf(fc * (float)(mk * mk)) * (1.f / N);
        P[i].x *= F; P[i].y *= F;
    }
    fft2048_reg<+1>(P, A, B, tid);         // Psm in regs

    float2* Tpo = Tp + ((size_t)bl * NSC + sidx) * N;
    #pragma unroll
    for (int i = 0; i < 8; ++i) Tpo[tid + i * NT] = P[i];

    // --- C chain ---
    fft2048_reg<-1>(C, A, B, tid);
    #pragma unroll
    for (int i = 0; i < 8; ++i) {
        int   k  = tid + i * NT;
        int   mk = min(k, N - k);
        float F  = expf(fc * (float)(mk * mk)) * (1.f / N);
        C[i].x *= F; C[i].y *= F;
    }
    fft2048_reg<+1>(C, A, B, tid);         // Csm in regs

    float2* Tco = Tc + ((size_t)bl * NSC + sidx) * N;
    #pragma unroll
    for (int i = 0; i < 8; ++i) Tco[tid + i * NT] = C[i];
}

// ---------------- K3: scale-axis boxcar conv + coherence + scale sum --------
__global__ __launch_bounds__(NT) void k_coh(const float2* __restrict__ Tp,
                                            const float2* __restrict__ Tc,
                                            float* __restrict__ coh, int b0) {
    const int bl = blockIdx.x >> 3;
    const int t  = ((blockIdx.x & 7) << 8) + threadIdx.x;
    const int b  = b0 + bl;
    const float2* colp = Tp + (size_t)bl * NSC * N + t;
    const float2* colc = Tc + (size_t)bl * NSC * N + t;

    float2 qp[10], qc[10];
    #pragma unroll
    for (int i = 0; i < 10; ++i) { qp[i] = make_float2(0.f, 0.f); qc[i] = make_float2(0.f, 0.f); }
    #pragma unroll
    for (int i = 0; i < 5; ++i) {
        qp[5 + i] = colp[(size_t)i * N];
        qc[5 + i] = colc[(size_t)i * N];
    }

    float acc = 0.f;
    const float w9 = 1.f / 9.f;
    for (int i = 0; i < NSC; ++i) {
        float sx = 0.f, sy = 0.f, sz = 0.f, sw = 0.f;
        #pragma unroll
        for (int k = 0; k < 10; ++k) { sx += qp[k].x; sy += qp[k].y; sz += qc[k].x; sw += qc[k].y; }
        float s1 = (sx - 0.5f * (qp[0].x + qp[9].x)) * w9;
        float s2 = (sy - 0.5f * (qp[0].y + qp[9].y)) * w9;
        float sr = (sz - 0.5f * (qc[0].x + qc[9].x)) * w9;
        float si = (sw - 0.5f * (qc[0].y + qc[9].y)) * w9;
        acc += (sr * sr + si * si) / (s1 * s2);
        #pragma unroll
        for (int k = 0; k < 9; ++k) { qp[k] = qp[k + 1]; qc[k] = qc[k + 1]; }
        int c = i + 5;
        if (c < NSC) {
            qp[9] = colp[(size_t)c * N];
            qc[9] = colc[(size_t)c * N];
        } else {
            qp[9] = make_float2(0.f, 0.f);
            qc[9] = make_float2(0.f, 0.f);
        }
    }
    coh[(size_t)b * N + t] = acc;
}

// ---------------- K4: sliding-window sum over time ----------------
__global__ __launch_bounds__(NT) void k_win(const float* __restrict__ coh,
                                            float* __restrict__ out) {
    __shared__ float row[N];
    const int b   = blockIdx.x;
    const int tid = threadIdx.x;
    for (int i = tid; i < N; i += NT) row[i] = coh[(size_t)b * N + i];
    __syncthreads();
    for (int t0 = tid; t0 < NOUT; t0 += NT) {
        float ssum = 0.f;
        for (int k = 0; k < WS_WIN; ++k) ssum += row[t0 + k];
        out[(size_t)b * NOUT + t0] = ssum;
    }
}

// ---------------- host launcher ----------------
extern "C" void kernel_launch(void* const* d_in, const int* in_sizes, int n_in,
                              void* d_out, int out_size, void* d_ws, size_t ws_size,
                              hipStream_t stream) {
    const float* x   = (const float*)d_in[0];
    float*       out = (float*)d_out;
    char*        ws  = (char*)d_ws;

    const size_t spec_bytes = (size_t)BATCH * 2 * N * sizeof(float2); // 2 MB
    const size_t coh_bytes  = (size_t)BATCH * N * sizeof(float);      // 512 KB
    const size_t perBatchT  = (size_t)NSC * N * sizeof(float4);       // Tp+Tc per batch

    float2* spec = (float2*)ws;
    float*  coh  = (float*)(ws + spec_bytes);
    char*   Tbase = ws + spec_bytes + coh_bytes;

    size_t avail = (ws_size > spec_bytes + coh_bytes) ? (ws_size - spec_bytes - coh_bytes) : 0;
    int chunk = (int)(avail / perBatchT);
    if (chunk < 1) chunk = 1;
    if (chunk > BATCH) chunk = BATCH;

    // planar layout: Tp plane then Tc plane, each chunk*NSC*N float2
    float2* Tp = (float2*)Tbase;
    float2* Tc = Tp + (size_t)chunk * NSC * N;

    k_fft_in<<<BATCH * 2, NT, 0, stream>>>(x, spec);
    for (int b0 = 0; b0 < BATCH; b0 += chunk) {
        int cb = BATCH - b0 < chunk ? BATCH - b0 : chunk;
        k_wct<<<cb * NSC, NT, 0, stream>>>(spec, Tp, Tc, b0);
        k_coh<<<cb * 8, NT, 0, stream>>>(Tp, Tc, coh, b0);
    }
    k_win<<<BATCH, NT, 0, stream>>>(coh, out);
}

// Round 7
// 217.355 us; speedup vs baseline: 2.0012x; 1.9867x over previous
//
#include <hip/hip_runtime.h>
#include <math.h>

// ---------------- problem constants ----------------
#define N        2048
#define NT       256      // threads per block
#define NSC      81       // number of scales (J+1)
#define BATCH    64
#define WS_WIN   94       // sliding window = 32*3-2
#define NOUT     1955     // N - WS_WIN + 1
#define DT_S     0.1f
#define W0_C     6.0f
#define PI_F     3.14159265358979f
#define TWOPI_F  6.28318530717959f
#define PIM14    0.7511255444649425f   // pi^(-1/4)
#define C_SQ2H   0.70710678118654752f  // sqrt(2)/2

// pad-swizzle: +1 element every 16 keeps every stage's b64 pattern at the
// 4-lane/bank-pair bandwidth floor
#define SWZ(e)   ((e) + ((e) >> 4))
#define LDSN     2176     // 2048 + 128 pad elements

__device__ __forceinline__ float2 cadd2(float2 a, float2 b) { return make_float2(a.x + b.x, a.y + b.y); }
__device__ __forceinline__ float2 csub2(float2 a, float2 b) { return make_float2(a.x - b.x, a.y - b.y); }
__device__ __forceinline__ float2 cmul2(float2 a, float2 b) { return make_float2(a.x * b.x - a.y * b.y, a.x * b.y + a.y * b.x); }

// 8-point DFT, natural-order outputs (sign SGN)
template<int SGN>
__device__ __forceinline__ void dft8(const float2 (&x)[8], float2 (&y)[8]) {
    const float s = (float)SGN;
    float2 t0 = cadd2(x[0], x[4]), t1 = cadd2(x[1], x[5]);
    float2 t2 = cadd2(x[2], x[6]), t3 = cadd2(x[3], x[7]);
    float2 u0 = csub2(x[0], x[4]);
    float2 d1 = csub2(x[1], x[5]);
    float2 d2 = csub2(x[2], x[6]);
    float2 d3 = csub2(x[3], x[7]);
    float2 u1 = make_float2(C_SQ2H * (d1.x - s * d1.y), C_SQ2H * (d1.y + s * d1.x));
    float2 u2 = make_float2(-s * d2.y, s * d2.x);
    float2 u3 = make_float2(-C_SQ2H * (d3.x + s * d3.y), C_SQ2H * (s * d3.x - d3.y));
    float2 a0 = cadd2(t0, t2), a1 = cadd2(t1, t3), b0 = csub2(t0, t2), e1 = csub2(t1, t3);
    float2 b1 = make_float2(-s * e1.y, s * e1.x);
    y[0] = cadd2(a0, a1); y[4] = csub2(a0, a1); y[2] = cadd2(b0, b1); y[6] = csub2(b0, b1);
    float2 c0 = cadd2(u0, u2), c1 = cadd2(u1, u3), g0 = csub2(u0, u2), h1 = csub2(u1, u3);
    float2 g1 = make_float2(-s * h1.y, s * h1.x);
    y[1] = cadd2(c0, c1); y[5] = csub2(c0, c1); y[3] = cadd2(g0, g1); y[7] = csub2(g0, g1);
}

// twiddle by w^u (w = exp(SGN*2pi*i*jm/N)) and scatter-store
template<int SGN>
__device__ __forceinline__ void twiddle_store(const float2 (&y)[8], float2* __restrict__ dst,
                                              int jm, int base, int m) {
    float ang = (float)SGN * (TWOPI_F / (float)N) * (float)jm;
    float sn, cs; __sincosf(ang, &sn, &cs);
    float2 w1 = make_float2(cs, sn);
    float2 w2 = cmul2(w1, w1);
    float2 w3 = cmul2(w2, w1);
    float2 w4 = cmul2(w2, w2);
    float2 w5 = cmul2(w3, w2);
    float2 w6 = cmul2(w3, w3);
    float2 w7 = cmul2(w4, w3);
    dst[SWZ(base)]         = y[0];
    dst[SWZ(base + m)]     = cmul2(y[1], w1);
    dst[SWZ(base + 2 * m)] = cmul2(y[2], w2);
    dst[SWZ(base + 3 * m)] = cmul2(y[3], w3);
    dst[SWZ(base + 4 * m)] = cmul2(y[4], w4);
    dst[SWZ(base + 5 * m)] = cmul2(y[5], w5);
    dst[SWZ(base + 6 * m)] = cmul2(y[6], w6);
    dst[SWZ(base + 7 * m)] = cmul2(y[7], w7);
}

// stage 1 (m=1): input from registers x[p] = element tid + p*256
template<int SGN>
__device__ __forceinline__ void stage1_reg(const float2 (&x)[8], float2* __restrict__ dst, int tid) {
    float2 y[8];
    dft8<SGN>(x, y);
    twiddle_store<SGN>(y, dst, tid, 8 * tid, 1);
}

// middle radix-8 stage, LDS -> LDS
template<int SGN>
__device__ __forceinline__ void stage8_lds(const float2* __restrict__ src,
                                           float2* __restrict__ dst, int q, int shift) {
    float2 xin[8];
    #pragma unroll
    for (int p = 0; p < 8; ++p) xin[p] = src[SWZ(q + p * 256)];
    float2 y[8];
    dft8<SGN>(xin, y);
    const int m  = 1 << shift;
    const int jm = q & ~(m - 1);
    twiddle_store<SGN>(y, dst, jm, q + 7 * jm, m);
}

// final radix-4 stage (m=512, j=0, no twiddles): outputs land back in regs,
// x[2u+qq] = element tid + (2u+qq)*256  (natural order, thread-owned)
template<int SGN>
__device__ __forceinline__ void stage4_regs(const float2* __restrict__ src, float2 (&x)[8], int tid) {
    const float s = (float)SGN;
    #pragma unroll
    for (int qq = 0; qq < 2; ++qq) {
        int q = tid + qq * 256;
        float2 x0 = src[SWZ(q)];
        float2 x1 = src[SWZ(q + 512)];
        float2 x2 = src[SWZ(q + 1024)];
        float2 x3 = src[SWZ(q + 1536)];
        float2 a0 = cadd2(x0, x2), a1 = cadd2(x1, x3);
        float2 b0 = csub2(x0, x2), e1 = csub2(x1, x3);
        float2 b1 = make_float2(-s * e1.y, s * e1.x);
        x[0 + qq] = cadd2(a0, a1);
        x[2 + qq] = cadd2(b0, b1);
        x[4 + qq] = csub2(a0, a1);
        x[6 + qq] = csub2(b0, b1);
    }
}

// full 2048-pt FFT, register in / register out (x[i] = element tid + i*256).
// SGN=-1: forward (numpy fft). SGN=+1: inverse exponent (1/N not applied).
template<int SGN>
__device__ __forceinline__ void fft2048_reg(float2 (&x)[8], float2* A, float2* B, int tid) {
    __syncthreads();                     // protect B from previous FFT's reads
    stage1_reg<SGN>(x, B, tid);          // regs -> B   (m=1)
    __syncthreads();
    stage8_lds<SGN>(B, A, tid, 3);       // B -> A      (m=8)
    __syncthreads();
    stage8_lds<SGN>(A, B, tid, 6);       // A -> B      (m=64)
    __syncthreads();
    stage4_regs<SGN>(B, x, tid);         // B -> regs   (m=512)
}

// ---------------- K1: normalize + forward FFT of each signal ----------------
__global__ __launch_bounds__(NT) void k_fft_in(const float* __restrict__ x,
                                               float2* __restrict__ spec) {
    __shared__ float2 A[LDSN];
    __shared__ float2 B[LDSN];
    __shared__ float  rs[NT], rq[NT];
    const int    tid = threadIdx.x;
    const float* y   = x + (size_t)blockIdx.x * N;

    float v[8];
    float lsum = 0.f, lsq = 0.f;
    #pragma unroll
    for (int i = 0; i < 8; ++i) {
        float t = y[tid + i * NT];
        v[i] = t; lsum += t; lsq += t * t;
    }
    rs[tid] = lsum; rq[tid] = lsq;
    __syncthreads();
    for (int o = NT / 2; o > 0; o >>= 1) {
        if (tid < o) { rs[tid] += rs[tid + o]; rq[tid] += rq[tid + o]; }
        __syncthreads();
    }
    const float mean = rs[0] * (1.f / N);
    const float var  = rq[0] * (1.f / N) - mean * mean;
    const float inv  = rsqrtf(var);

    float2 z[8];
    #pragma unroll
    for (int i = 0; i < 8; ++i) z[i] = make_float2((v[i] - mean) * inv, 0.f);

    fft2048_reg<-1>(z, A, B, tid);

    float2* o2 = spec + (size_t)blockIdx.x * N;
    #pragma unroll
    for (int i = 0; i < 8; ++i) o2[tid + i * NT] = z[i];
}

// ---------------- K2: per (batch, scale) CWT + smoothing ----------------
// Allocator-proof design: gfx950's allocator insists on 64 VGPRs (R3-R6:
// every bounds/attribute combo still landed 64-84 and spilled 0.15-1.4 GB).
// So nothing is held in registers ACROSS an FFT call: the one array that
// must survive (w1 during FFT(w2); C during the P chain) is parked in a
// third LDS stash S via thread-owned indices (no barriers needed, b64
// conflict-free). Peak live set ~45-50 VGPRs -> fits 64 with zero spill.
// LDS 17+17+16 = 50 KB -> 3 blocks/CU.
__global__ __launch_bounds__(NT) void k_wct(const float2* __restrict__ spec,
                                            float2* __restrict__ Tp,
                                            float2* __restrict__ Tc, int b0) {
    __shared__ float2 A[LDSN];
    __shared__ float2 B[LDSN];
    __shared__ float2 S[N];          // park stash, thread-owned access only
    const int tid  = threadIdx.x;
    const int sidx = blockIdx.x % NSC;
    const int bl   = blockIdx.x / NSC;
    const int b    = b0 + bl;

    const float s0    = 2.f * DT_S * (W0_C + sqrtf(2.f + W0_C * W0_C)) / (4.f * PI_F);
    const float s     = s0 * exp2f(0.125f * (float)sidx);
    const float inv_s = 1.f / s;

    const float2* yh1 = spec + (size_t)(b * 2 + 0) * N;
    const float2* yh2 = spec + (size_t)(b * 2 + 1) * N;

    // Morlet filter (w>0 one-sided), unit-energy norm, ifft 1/N folded in
    const float nrm   = PIM14 * sqrtf(TWOPI_F * s / DT_S) * (1.f / N);
    const float wstep = TWOPI_F / ((float)N * DT_S);

    // ---- W1 = ifft(filter * yh1), then park in S ----
    {
        float2 w[8];
        #pragma unroll
        for (int i = 0; i < 8; ++i) {
            int   k = tid + i * NT;
            float f = 0.f;
            if (k >= 1 && k < N / 2) {
                float arg = s * (wstep * (float)k) - W0_C;
                f = nrm * expf(-0.5f * arg * arg);
            }
            float2 a = yh1[k];
            w[i] = make_float2(a.x * f, a.y * f);
        }
        fft2048_reg<+1>(w, A, B, tid);
        #pragma unroll
        for (int i = 0; i < 8; ++i) S[tid + i * NT] = w[i];   // park (own slots)
    }

    // ---- W2 = ifft(filter * yh2) ----
    float2 w2[8];
    #pragma unroll
    for (int i = 0; i < 8; ++i) {
        int   k = tid + i * NT;
        float f = 0.f;                      // recompute filter (keeps live set small)
        if (k >= 1 && k < N / 2) {
            float arg = s * (wstep * (float)k) - W0_C;
            f = nrm * expf(-0.5f * arg * arg);
        }
        float2 c = yh2[k];
        w2[i] = make_float2(c.x * f, c.y * f);
    }
    fft2048_reg<+1>(w2, A, B, tid);

    // ---- products; P stays in regs, C parked in S (overwrites W1 slots) ----
    float2 P[8];
    #pragma unroll
    for (int i = 0; i < 8; ++i) {
        float2 a = S[tid + i * NT];          // unpark W1 (own slots)
        float2 c = w2[i];
        P[i] = make_float2((a.x * a.x + a.y * a.y) * inv_s,
                           (c.x * c.x + c.y * c.y) * inv_s);
        S[tid + i * NT] = make_float2((a.x * c.x + a.y * c.y) * inv_s,
                                      (a.y * c.x - a.x * c.y) * inv_s);  // park C
    }

    // Gaussian time-smoothing in Fourier domain (1/N folded into F)
    const float sdt = s / DT_S;
    const float fc  = -0.5f * sdt * sdt * (TWOPI_F / (float)N) * (TWOPI_F / (float)N);

    // --- P chain: fft -> filter -> ifft -> store ---
    fft2048_reg<-1>(P, A, B, tid);
    #pragma unroll
    for (int i = 0; i < 8; ++i) {
        int   k  = tid + i * NT;
        int   mk = min(k, N - k);
        float F  = expf(fc * (float)(mk * mk)) * (1.f / N);
        P[i].x *= F; P[i].y *= F;
    }
    fft2048_reg<+1>(P, A, B, tid);

    float2* Tpo = Tp + ((size_t)bl * NSC + sidx) * N;
    #pragma unroll
    for (int i = 0; i < 8; ++i) Tpo[tid + i * NT] = P[i];

    // --- C chain: unpark, fft -> filter -> ifft -> store ---
    float2 C[8];
    #pragma unroll
    for (int i = 0; i < 8; ++i) C[i] = S[tid + i * NT];       // unpark C

    fft2048_reg<-1>(C, A, B, tid);
    #pragma unroll
    for (int i = 0; i < 8; ++i) {
        int   k  = tid + i * NT;
        int   mk = min(k, N - k);
        float F  = expf(fc * (float)(mk * mk)) * (1.f / N);
        C[i].x *= F; C[i].y *= F;
    }
    fft2048_reg<+1>(C, A, B, tid);

    float2* Tco = Tc + ((size_t)bl * NSC + sidx) * N;
    #pragma unroll
    for (int i = 0; i < 8; ++i) Tco[tid + i * NT] = C[i];
}

// ---------------- K3: scale-axis boxcar conv + coherence + scale sum --------
__global__ __launch_bounds__(NT) void k_coh(const float2* __restrict__ Tp,
                                            const float2* __restrict__ Tc,
                                            float* __restrict__ coh, int b0) {
    const int bl = blockIdx.x >> 3;
    const int t  = ((blockIdx.x & 7) << 8) + threadIdx.x;
    const int b  = b0 + bl;
    const float2* colp = Tp + (size_t)bl * NSC * N + t;
    const float2* colc = Tc + (size_t)bl * NSC * N + t;

    float2 qp[10], qc[10];
    #pragma unroll
    for (int i = 0; i < 10; ++i) { qp[i] = make_float2(0.f, 0.f); qc[i] = make_float2(0.f, 0.f); }
    #pragma unroll
    for (int i = 0; i < 5; ++i) {
        qp[5 + i] = colp[(size_t)i * N];
        qc[5 + i] = colc[(size_t)i * N];
    }

    float acc = 0.f;
    const float w9 = 1.f / 9.f;
    for (int i = 0; i < NSC; ++i) {
        float sx = 0.f, sy = 0.f, sz = 0.f, sw = 0.f;
        #pragma unroll
        for (int k = 0; k < 10; ++k) { sx += qp[k].x; sy += qp[k].y; sz += qc[k].x; sw += qc[k].y; }
        float s1 = (sx - 0.5f * (qp[0].x + qp[9].x)) * w9;
        float s2 = (sy - 0.5f * (qp[0].y + qp[9].y)) * w9;
        float sr = (sz - 0.5f * (qc[0].x + qc[9].x)) * w9;
        float si = (sw - 0.5f * (qc[0].y + qc[9].y)) * w9;
        acc += (sr * sr + si * si) / (s1 * s2);
        #pragma unroll
        for (int k = 0; k < 9; ++k) { qp[k] = qp[k + 1]; qc[k] = qc[k + 1]; }
        int c = i + 5;
        if (c < NSC) {
            qp[9] = colp[(size_t)c * N];
            qc[9] = colc[(size_t)c * N];
        } else {
            qp[9] = make_float2(0.f, 0.f);
            qc[9] = make_float2(0.f, 0.f);
        }
    }
    coh[(size_t)b * N + t] = acc;
}

// ---------------- K4: sliding-window sum over time ----------------
__global__ __launch_bounds__(NT) void k_win(const float* __restrict__ coh,
                                            float* __restrict__ out) {
    __shared__ float row[N];
    const int b   = blockIdx.x;
    const int tid = threadIdx.x;
    for (int i = tid; i < N; i += NT) row[i] = coh[(size_t)b * N + i];
    __syncthreads();
    for (int t0 = tid; t0 < NOUT; t0 += NT) {
        float ssum = 0.f;
        for (int k = 0; k < WS_WIN; ++k) ssum += row[t0 + k];
        out[(size_t)b * NOUT + t0] = ssum;
    }
}

// ---------------- host launcher ----------------
extern "C" void kernel_launch(void* const* d_in, const int* in_sizes, int n_in,
                              void* d_out, int out_size, void* d_ws, size_t ws_size,
                              hipStream_t stream) {
    const float* x   = (const float*)d_in[0];
    float*       out = (float*)d_out;
    char*        ws  = (char*)d_ws;

    const size_t spec_bytes = (size_t)BATCH * 2 * N * sizeof(float2); // 2 MB
    const size_t coh_bytes  = (size_t)BATCH * N * sizeof(float);      // 512 KB
    const size_t perBatchT  = (size_t)NSC * N * sizeof(float4);       // Tp+Tc per batch

    float2* spec = (float2*)ws;
    float*  coh  = (float*)(ws + spec_bytes);
    char*   Tbase = ws + spec_bytes + coh_bytes;

    size_t avail = (ws_size > spec_bytes + coh_bytes) ? (ws_size - spec_bytes - coh_bytes) : 0;
    int chunk = (int)(avail / perBatchT);
    if (chunk < 1) chunk = 1;
    if (chunk > BATCH) chunk = BATCH;

    // planar layout: Tp plane then Tc plane, each chunk*NSC*N float2
    float2* Tp = (float2*)Tbase;
    float2* Tc = Tp + (size_t)chunk * NSC * N;

    k_fft_in<<<BATCH * 2, NT, 0, stream>>>(x, spec);
    for (int b0 = 0; b0 < BATCH; b0 += chunk) {
        int cb = BATCH - b0 < chunk ? BATCH - b0 : chunk;
        k_wct<<<cb * NSC, NT, 0, stream>>>(spec, Tp, Tc, b0);
        k_coh<<<cb * 8, NT, 0, stream>>>(Tp, Tc, coh, b0);
    }
    k_win<<<BATCH, NT, 0, stream>>>(coh, out);
}

// Round 8
// 207.067 us; speedup vs baseline: 2.1006x; 1.0497x over previous
//
#include <hip/hip_runtime.h>
#include <math.h>

// ---------------- problem constants ----------------
#define N        2048
#define NT       256      // threads per block
#define NSC      81       // number of scales (J+1)
#define BATCH    64
#define WS_WIN   94       // sliding window = 32*3-2
#define NOUT     1955     // N - WS_WIN + 1
#define DT_S     0.1f
#define W0_C     6.0f
#define PI_F     3.14159265358979f
#define TWOPI_F  6.28318530717959f
#define PIM14    0.7511255444649425f   // pi^(-1/4)
#define C_SQ2H   0.70710678118654752f  // sqrt(2)/2

// pad-swizzle: +1 element every 16 (conflict mitigation). All stage addresses
// below are hand-decomposed into per-thread base + compile-time offsets
// (exactness of each decomposition verified algebraically: no carries cross
// the >>4 boundary for the given strides).
#define SWZ(e)   ((e) + ((e) >> 4))
#define LDSN     2176     // 2048 + 128 pad elements

// packed 2xfp32 complex: backend emits v_pk_add_f32 / v_pk_mul_f32 / v_pk_fma_f32
typedef float v2f __attribute__((ext_vector_type(2)));

__device__ __forceinline__ v2f shuf10(v2f a) { return __builtin_shufflevector(a, a, 1, 0); }
__device__ __forceinline__ v2f splat0(v2f a) { return __builtin_shufflevector(a, a, 0, 0); }
__device__ __forceinline__ v2f splat1(v2f a) { return __builtin_shufflevector(a, a, 1, 1); }

// complex multiply: (a.x b.x - a.y b.y, a.x b.y + a.y b.x) — 3 pk ops
__device__ __forceinline__ v2f cmul(v2f a, v2f b) {
    const v2f sgn = {-1.f, 1.f};
    return splat0(a) * b + sgn * (splat1(a) * shuf10(b));
}

// multiply by s*i (s=SGN): (-s*a.y, s*a.x) — shuffle + 1 pk mul
template<int SGN>
__device__ __forceinline__ v2f muli(v2f a) {
    const v2f sgn = {-(float)SGN, (float)SGN};
    return sgn * shuf10(a);
}

// 8-point DFT, natural-order outputs (sign SGN) — same algebra as R1-R7
template<int SGN>
__device__ __forceinline__ void dft8(const v2f (&x)[8], v2f (&y)[8]) {
    v2f t0 = x[0] + x[4], t1 = x[1] + x[5], t2 = x[2] + x[6], t3 = x[3] + x[7];
    v2f u0 = x[0] - x[4], d1 = x[1] - x[5], d2 = x[2] - x[6], d3 = x[3] - x[7];
    v2f u1 = C_SQ2H * (d1 + muli<SGN>(d1));
    v2f u2 = muli<SGN>(d2);
    v2f u3 = C_SQ2H * (muli<SGN>(d3) - d3);
    v2f a0 = t0 + t2, a1 = t1 + t3, b0 = t0 - t2, b1 = muli<SGN>(t1 - t3);
    y[0] = a0 + a1; y[4] = a0 - a1; y[2] = b0 + b1; y[6] = b0 - b1;
    v2f c0 = u0 + u2, c1 = u1 + u3, g0 = u0 - u2, g1 = muli<SGN>(u1 - u3);
    y[1] = c0 + c1; y[5] = c0 - c1; y[3] = g0 + g1; y[7] = g0 - g1;
}

// twiddle powers w^1..w^7, w = exp(SGN*2pi*i*jm/N)
template<int SGN>
__device__ __forceinline__ void twiddles(int jm, v2f (&w)[8]) {
    float ang = (float)SGN * (TWOPI_F / (float)N) * (float)jm;
    float sn, cs; __sincosf(ang, &sn, &cs);
    w[1] = (v2f){cs, sn};
    w[2] = cmul(w[1], w[1]);
    w[3] = cmul(w[2], w[1]);
    w[4] = cmul(w[2], w[2]);
    w[5] = cmul(w[3], w[2]);
    w[6] = cmul(w[3], w[3]);
    w[7] = cmul(w[4], w[3]);
}

// stage 1 (m=1): regs -> LDS. idx = 8*tid + u; SWZ(8tid+u) = 8tid+(tid>>1)+u (exact)
template<int SGN>
__device__ __forceinline__ void stage1_reg(const v2f (&x)[8], v2f* __restrict__ dst, int tid) {
    v2f y[8];
    dft8<SGN>(x, y);
    v2f w[8];
    twiddles<SGN>(tid, w);
    const int wb = 8 * tid + (tid >> 1);
    dst[wb]     = y[0];
    dst[wb + 1] = cmul(y[1], w[1]);
    dst[wb + 2] = cmul(y[2], w[2]);
    dst[wb + 3] = cmul(y[3], w[3]);
    dst[wb + 4] = cmul(y[4], w[4]);
    dst[wb + 5] = cmul(y[5], w[5]);
    dst[wb + 6] = cmul(y[6], w[6]);
    dst[wb + 7] = cmul(y[7], w[7]);
}

// stage m=8: LDS -> LDS. reads SWZ(tid+256p) = SWZ(tid)+272p;
// writes SWZ(64j+k+8u) = (68j+k) + {0,8,17,25,34,42,51,59}[u]  (j=tid>>3,k=tid&7)
template<int SGN>
__device__ __forceinline__ void stage8_m8(const v2f* __restrict__ src,
                                          v2f* __restrict__ dst, int tid) {
    const int rb = tid + (tid >> 4);
    v2f xin[8];
    #pragma unroll
    for (int p = 0; p < 8; ++p) xin[p] = src[rb + 272 * p];
    v2f y[8];
    dft8<SGN>(xin, y);
    const int j = tid >> 3, k = tid & 7;
    v2f w[8];
    twiddles<SGN>(8 * j, w);
    const int wb = 68 * j + k;
    dst[wb]      = y[0];
    dst[wb + 8]  = cmul(y[1], w[1]);
    dst[wb + 17] = cmul(y[2], w[2]);
    dst[wb + 25] = cmul(y[3], w[3]);
    dst[wb + 34] = cmul(y[4], w[4]);
    dst[wb + 42] = cmul(y[5], w[5]);
    dst[wb + 51] = cmul(y[6], w[6]);
    dst[wb + 59] = cmul(y[7], w[7]);
}

// stage m=64: LDS -> LDS. reads SWZ(tid)+272p; writes SWZ(base)+68u, base=tid+448*(tid>>6)
template<int SGN>
__device__ __forceinline__ void stage8_m64(const v2f* __restrict__ src,
                                           v2f* __restrict__ dst, int tid) {
    const int rb = tid + (tid >> 4);
    v2f xin[8];
    #pragma unroll
    for (int p = 0; p < 8; ++p) xin[p] = src[rb + 272 * p];
    v2f y[8];
    dft8<SGN>(xin, y);
    const int j = tid >> 6;
    v2f w[8];
    twiddles<SGN>(64 * j, w);
    const int base = tid + 448 * j;
    const int wb   = base + (base >> 4);
    dst[wb]          = y[0];
    dst[wb + 68]     = cmul(y[1], w[1]);
    dst[wb + 2 * 68] = cmul(y[2], w[2]);
    dst[wb + 3 * 68] = cmul(y[3], w[3]);
    dst[wb + 4 * 68] = cmul(y[4], w[4]);
    dst[wb + 5 * 68] = cmul(y[5], w[5]);
    dst[wb + 6 * 68] = cmul(y[6], w[6]);
    dst[wb + 7 * 68] = cmul(y[7], w[7]);
}

// final radix-4 stage (m=512, j=0, no twiddles): LDS -> regs.
// reads SWZ(q+512p) = SWZ(q)+544p; x[2u+qq] = element tid+(2u+qq)*256
template<int SGN>
__device__ __forceinline__ void stage4_regs(const v2f* __restrict__ src, v2f (&x)[8], int tid) {
    #pragma unroll
    for (int qq = 0; qq < 2; ++qq) {
        const int q  = tid + qq * 256;
        const int rb = q + (q >> 4);
        v2f x0 = src[rb];
        v2f x1 = src[rb + 544];
        v2f x2 = src[rb + 2 * 544];
        v2f x3 = src[rb + 3 * 544];
        v2f a0 = x0 + x2, a1 = x1 + x3;
        v2f b0 = x0 - x2, b1 = muli<SGN>(x1 - x3);
        x[0 + qq] = a0 + a1;
        x[2 + qq] = b0 + b1;
        x[4 + qq] = a0 - a1;
        x[6 + qq] = b0 - b1;
    }
}

// full 2048-pt FFT, register in / register out (x[i] = element tid + i*256).
// SGN=-1: forward (numpy fft). SGN=+1: inverse exponent (1/N not applied).
template<int SGN>
__device__ __forceinline__ void fft2048_reg(v2f (&x)[8], v2f* A, v2f* B, int tid) {
    __syncthreads();                 // protect B from previous FFT's reads
    stage1_reg<SGN>(x, B, tid);      // regs -> B   (m=1)
    __syncthreads();
    stage8_m8<SGN>(B, A, tid);       // B -> A      (m=8)
    __syncthreads();
    stage8_m64<SGN>(A, B, tid);      // A -> B      (m=64)
    __syncthreads();
    stage4_regs<SGN>(B, x, tid);     // B -> regs   (m=512)
}

// ---------------- K1: normalize + forward FFT of each signal ----------------
__global__ __launch_bounds__(NT) void k_fft_in(const float* __restrict__ x,
                                               v2f* __restrict__ spec) {
    __shared__ v2f A[LDSN];
    __shared__ v2f B[LDSN];
    __shared__ float rs[NT], rq[NT];
    const int    tid = threadIdx.x;
    const float* y   = x + (size_t)blockIdx.x * N;

    float v[8];
    float lsum = 0.f, lsq = 0.f;
    #pragma unroll
    for (int i = 0; i < 8; ++i) {
        float t = y[tid + i * NT];
        v[i] = t; lsum += t; lsq += t * t;
    }
    rs[tid] = lsum; rq[tid] = lsq;
    __syncthreads();
    for (int o = NT / 2; o > 0; o >>= 1) {
        if (tid < o) { rs[tid] += rs[tid + o]; rq[tid] += rq[tid + o]; }
        __syncthreads();
    }
    const float mean = rs[0] * (1.f / N);
    const float var  = rq[0] * (1.f / N) - mean * mean;
    const float inv  = rsqrtf(var);

    v2f z[8];
    #pragma unroll
    for (int i = 0; i < 8; ++i) z[i] = (v2f){(v[i] - mean) * inv, 0.f};

    fft2048_reg<-1>(z, A, B, tid);

    v2f* o2 = spec + (size_t)blockIdx.x * N;
    #pragma unroll
    for (int i = 0; i < 8; ++i) o2[tid + i * NT] = z[i];
}

// ---------------- K2: per (batch, scale) CWT + smoothing ----------------
// Allocator-proof structure (R7, kept): nothing held in registers across an
// FFT call — the surviving array is parked in LDS stash S at thread-owned
// indices. Peak live ~50 VGPRs. LDS 17+17+16 = 50 KB -> 3 blocks/CU.
__global__ __launch_bounds__(NT) void k_wct(const v2f* __restrict__ spec,
                                            v2f* __restrict__ Tp,
                                            v2f* __restrict__ Tc, int b0) {
    __shared__ v2f A[LDSN];
    __shared__ v2f B[LDSN];
    __shared__ v2f S[N];             // park stash, thread-owned access only
    const int tid  = threadIdx.x;
    const int sidx = blockIdx.x % NSC;
    const int bl   = blockIdx.x / NSC;
    const int b    = b0 + bl;

    const float s0    = 2.f * DT_S * (W0_C + sqrtf(2.f + W0_C * W0_C)) / (4.f * PI_F);
    const float s     = s0 * exp2f(0.125f * (float)sidx);
    const float inv_s = 1.f / s;

    const v2f* yh1 = spec + (size_t)(b * 2 + 0) * N;
    const v2f* yh2 = spec + (size_t)(b * 2 + 1) * N;

    // Morlet filter (w>0 one-sided), unit-energy norm, ifft 1/N folded in
    const float nrm   = PIM14 * sqrtf(TWOPI_F * s / DT_S) * (1.f / N);
    const float wstep = TWOPI_F / ((float)N * DT_S);

    // ---- W1 = ifft(filter * yh1), then park in S ----
    {
        v2f w[8];
        #pragma unroll
        for (int i = 0; i < 8; ++i) {
            int   k = tid + i * NT;
            float f = 0.f;
            if (k >= 1 && k < N / 2) {
                float arg = s * (wstep * (float)k) - W0_C;
                f = nrm * expf(-0.5f * arg * arg);
            }
            w[i] = yh1[k] * f;
        }
        fft2048_reg<+1>(w, A, B, tid);
        #pragma unroll
        for (int i = 0; i < 8; ++i) S[tid + i * NT] = w[i];   // park
    }

    // ---- W2 = ifft(filter * yh2) ----
    v2f w2[8];
    #pragma unroll
    for (int i = 0; i < 8; ++i) {
        int   k = tid + i * NT;
        float f = 0.f;                  // recompute filter (keeps live set small)
        if (k >= 1 && k < N / 2) {
            float arg = s * (wstep * (float)k) - W0_C;
            f = nrm * expf(-0.5f * arg * arg);
        }
        w2[i] = yh2[k] * f;
    }
    fft2048_reg<+1>(w2, A, B, tid);

    // ---- products; P stays in regs, C parked in S (overwrites W1 slots) ----
    v2f P[8];
    #pragma unroll
    for (int i = 0; i < 8; ++i) {
        v2f a = S[tid + i * NT];         // unpark W1
        v2f c = w2[i];
        P[i] = (v2f){(a.x * a.x + a.y * a.y) * inv_s,
                     (c.x * c.x + c.y * c.y) * inv_s};
        S[tid + i * NT] = (v2f){(a.x * c.x + a.y * c.y) * inv_s,
                                (a.y * c.x - a.x * c.y) * inv_s};  // park C
    }

    // Gaussian time-smoothing in Fourier domain (1/N folded into F)
    const float sdt = s / DT_S;
    const float fc  = -0.5f * sdt * sdt * (TWOPI_F / (float)N) * (TWOPI_F / (float)N);

    // --- P chain: fft -> filter -> ifft -> store ---
    fft2048_reg<-1>(P, A, B, tid);
    #pragma unroll
    for (int i = 0; i < 8; ++i) {
        int   k  = tid + i * NT;
        int   mk = min(k, N - k);
        float F  = expf(fc * (float)(mk * mk)) * (1.f / N);
        P[i] *= F;
    }
    fft2048_reg<+1>(P, A, B, tid);

    v2f* Tpo = Tp + ((size_t)bl * NSC + sidx) * N;
    #pragma unroll
    for (int i = 0; i < 8; ++i) Tpo[tid + i * NT] = P[i];

    // --- C chain: unpark, fft -> filter -> ifft -> store ---
    v2f C[8];
    #pragma unroll
    for (int i = 0; i < 8; ++i) C[i] = S[tid + i * NT];       // unpark C

    fft2048_reg<-1>(C, A, B, tid);
    #pragma unroll
    for (int i = 0; i < 8; ++i) {
        int   k  = tid + i * NT;
        int   mk = min(k, N - k);
        float F  = expf(fc * (float)(mk * mk)) * (1.f / N);
        C[i] *= F;
    }
    fft2048_reg<+1>(C, A, B, tid);

    v2f* Tco = Tc + ((size_t)bl * NSC + sidx) * N;
    #pragma unroll
    for (int i = 0; i < 8; ++i) Tco[tid + i * NT] = C[i];
}

// ---------------- K3: scale-axis boxcar conv + coherence + scale sum --------
__global__ __launch_bounds__(NT) void k_coh(const v2f* __restrict__ Tp,
                                            const v2f* __restrict__ Tc,
                                            float* __restrict__ coh, int b0) {
    const int bl = blockIdx.x >> 3;
    const int t  = ((blockIdx.x & 7) << 8) + threadIdx.x;
    const int b  = b0 + bl;
    const v2f* colp = Tp + (size_t)bl * NSC * N + t;
    const v2f* colc = Tc + (size_t)bl * NSC * N + t;

    v2f qp[10], qc[10];
    #pragma unroll
    for (int i = 0; i < 10; ++i) { qp[i] = (v2f){0.f, 0.f}; qc[i] = (v2f){0.f, 0.f}; }
    #pragma unroll
    for (int i = 0; i < 5; ++i) {
        qp[5 + i] = colp[(size_t)i * N];
        qc[5 + i] = colc[(size_t)i * N];
    }

    float acc = 0.f;
    const float w9 = 1.f / 9.f;
    for (int i = 0; i < NSC; ++i) {
        v2f sp = qp[0], sc = qc[0];
        #pragma unroll
        for (int k = 1; k < 10; ++k) { sp += qp[k]; sc += qc[k]; }
        v2f sv = (sp - 0.5f * (qp[0] + qp[9])) * w9;   // (S1, S2)
        v2f cv = (sc - 0.5f * (qc[0] + qc[9])) * w9;   // (S12.re, S12.im)
        acc += (cv.x * cv.x + cv.y * cv.y) / (sv.x * sv.y);
        #pragma unroll
        for (int k = 0; k < 9; ++k) { qp[k] = qp[k + 1]; qc[k] = qc[k + 1]; }
        int c = i + 5;
        if (c < NSC) {
            qp[9] = colp[(size_t)c * N];
            qc[9] = colc[(size_t)c * N];
        } else {
            qp[9] = (v2f){0.f, 0.f};
            qc[9] = (v2f){0.f, 0.f};
        }
    }
    coh[(size_t)b * N + t] = acc;
}

// ---------------- K4: sliding-window sum over time ----------------
__global__ __launch_bounds__(NT) void k_win(const float* __restrict__ coh,
                                            float* __restrict__ out) {
    __shared__ float row[N];
    const int b   = blockIdx.x;
    const int tid = threadIdx.x;
    for (int i = tid; i < N; i += NT) row[i] = coh[(size_t)b * N + i];
    __syncthreads();
    for (int t0 = tid; t0 < NOUT; t0 += NT) {
        float ssum = 0.f;
        for (int k = 0; k < WS_WIN; ++k) ssum += row[t0 + k];
        out[(size_t)b * NOUT + t0] = ssum;
    }
}

// ---------------- host launcher ----------------
extern "C" void kernel_launch(void* const* d_in, const int* in_sizes, int n_in,
                              void* d_out, int out_size, void* d_ws, size_t ws_size,
                              hipStream_t stream) {
    const float* x   = (const float*)d_in[0];
    float*       out = (float*)d_out;
    char*        ws  = (char*)d_ws;

    const size_t spec_bytes = (size_t)BATCH * 2 * N * sizeof(v2f);  // 2 MB
    const size_t coh_bytes  = (size_t)BATCH * N * sizeof(float);    // 512 KB
    const size_t perBatchT  = (size_t)NSC * N * 2 * sizeof(v2f);    // Tp+Tc per batch

    v2f*   spec  = (v2f*)ws;
    float* coh   = (float*)(ws + spec_bytes);
    char*  Tbase = ws + spec_bytes + coh_bytes;

    size_t avail = (ws_size > spec_bytes + coh_bytes) ? (ws_size - spec_bytes - coh_bytes) : 0;
    int chunk = (int)(avail / perBatchT);
    if (chunk < 1) chunk = 1;
    if (chunk > BATCH) chunk = BATCH;

    // planar layout: Tp plane then Tc plane, each chunk*NSC*N v2f
    v2f* Tp = (v2f*)Tbase;
    v2f* Tc = Tp + (size_t)chunk * NSC * N;

    k_fft_in<<<BATCH * 2, NT, 0, stream>>>(x, spec);
    for (int b0 = 0; b0 < BATCH; b0 += chunk) {
        int cb = BATCH - b0 < chunk ? BATCH - b0 : chunk;
        k_wct<<<cb * NSC, NT, 0, stream>>>(spec, Tp, Tc, b0);
        k_coh<<<cb * 8, NT, 0, stream>>>(Tp, Tc, coh, b0);
    }
    k_win<<<BATCH, NT, 0, stream>>>(coh, out);
}